// Round 1
// baseline (478.983 us; speedup 1.0000x reference)
//
#include <hip/hip_runtime.h>
#include <hip/hip_bf16.h>
#include <cstddef>

// fast tanh: 1 - 2/(exp(2x)+1); saturates correctly for |x| large (exp->inf -> 1)
__device__ __forceinline__ float fast_tanh(float x) {
    float e = __expf(2.0f * x);
    return 1.0f - 2.0f / (e + 1.0f);
}

// ---------------------------------------------------------------------------
// small setup kernel: pad c1_w [6*16][25] -> [6*16][28] (zero tail) so phase B
// can use aligned float4 loads.
__global__ void pad_w1_kernel(const float* __restrict__ src, float* __restrict__ dst) {
    int i = blockIdx.x * blockDim.x + threadIdx.x;
    if (i < 96 * 28) {
        int row = i / 28, t = i % 28;
        dst[i] = (t < 25) ? src[row * 25 + t] : 0.0f;
    }
}

// ---------------------------------------------------------------------------
// Kernel A: per image: conv0(SAME,5x5,1->16)+tanh in LDS, then
// conv1(VALID,5x5,16->6)+bias+tanh+avgpool2 -> out2 [B,6,14,14]
__global__ __launch_bounds__(256, 2) void lenet_front(
    const float* __restrict__ x,        // [B,1,32,32]
    const float* __restrict__ filters,  // [16,1,5,5]
    const float* __restrict__ w1pad,    // [96,28]
    const float* __restrict__ c1_b,     // [6]
    float* __restrict__ out2)           // [B,6,14,14]
{
    __shared__ float xs[36 * 36];       // zero-padded input
    __shared__ float s1[16 * 32 * 36];  // tanh(conv0), 16 ch, rows padded to 36

    const int b = blockIdx.x;
    const int tid = threadIdx.x;
    const float* xb = x + (size_t)b * 1024;

    for (int i = tid; i < 36 * 36; i += 256) xs[i] = 0.0f;
    __syncthreads();
    for (int i = tid; i < 1024; i += 256) {
        int r = i >> 5, c = i & 31;
        xs[(r + 2) * 36 + (c + 2)] = xb[i];
    }
    __syncthreads();

    // ---- Phase A: conv0 + tanh. 256 tasks: (y, 4-pixel group) ----
    {
        const int y = tid >> 3;
        const int x0 = (tid & 7) * 4;
        float win[40];  // 5 rows x 8 cols
#pragma unroll
        for (int i = 0; i < 5; i++) {
            const float4* p = (const float4*)&xs[(y + i) * 36 + x0];
            float4 a = p[0], q = p[1];
            win[i * 8 + 0] = a.x; win[i * 8 + 1] = a.y;
            win[i * 8 + 2] = a.z; win[i * 8 + 3] = a.w;
            win[i * 8 + 4] = q.x; win[i * 8 + 5] = q.y;
            win[i * 8 + 6] = q.z; win[i * 8 + 7] = q.w;
        }
#pragma unroll
        for (int oc = 0; oc < 16; oc++) {
            float a0 = 0.f, a1 = 0.f, a2 = 0.f, a3 = 0.f;
#pragma unroll
            for (int ky = 0; ky < 5; ky++) {
#pragma unroll
                for (int kx = 0; kx < 5; kx++) {
                    float w = filters[oc * 25 + ky * 5 + kx];  // uniform -> s_load
                    const float* wr = &win[ky * 8 + kx];
                    a0 += w * wr[0]; a1 += w * wr[1];
                    a2 += w * wr[2]; a3 += w * wr[3];
                }
            }
            int base = (oc * 32 + y) * 36 + x0;
            s1[base + 0] = fast_tanh(a0);
            s1[base + 1] = fast_tanh(a1);
            s1[base + 2] = fast_tanh(a2);
            s1[base + 3] = fast_tanh(a3);
        }
    }
    __syncthreads();

    // ---- Phase B: conv1 + bias + tanh + avgpool. 168 tasks: (oc, py, half) ----
    if (tid < 168) {
        const int oc = tid / 28;
        const int r = tid % 28;
        const int py = r >> 1;
        const int h = r & 1;
        const int x0 = h * 14;   // conv col base (14 conv cols -> 7 pooled)
        const int y0 = py * 2;   // conv row base (2 conv rows -> 1 pooled row)

        float acc[2][14];
#pragma unroll
        for (int i = 0; i < 2; i++)
#pragma unroll
            for (int j = 0; j < 14; j++) acc[i][j] = 0.f;

        const float* wbase = w1pad + oc * 16 * 28;
#pragma unroll 1
        for (int ic = 0; ic < 16; ic++) {
            float w[28];
            const float4* wp = (const float4*)(wbase + ic * 28);
#pragma unroll
            for (int q = 0; q < 7; q++) {
                float4 v = wp[q];
                w[4 * q + 0] = v.x; w[4 * q + 1] = v.y;
                w[4 * q + 2] = v.z; w[4 * q + 3] = v.w;
            }
#pragma unroll
            for (int t6 = 0; t6 < 6; t6++) {
                const int iy = y0 + t6;
                float seg[18];
                const float2* sp = (const float2*)&s1[(ic * 32 + iy) * 36 + x0];
#pragma unroll
                for (int q = 0; q < 9; q++) {
                    float2 v = sp[q];
                    seg[2 * q] = v.x; seg[2 * q + 1] = v.y;
                }
                if (t6 < 5) {  // contributes to conv row y0 with ky=t6
#pragma unroll
                    for (int kx = 0; kx < 5; kx++) {
                        float wv = w[t6 * 5 + kx];
#pragma unroll
                        for (int j = 0; j < 14; j++) acc[0][j] += wv * seg[kx + j];
                    }
                }
                if (t6 >= 1) {  // contributes to conv row y0+1 with ky=t6-1
#pragma unroll
                    for (int kx = 0; kx < 5; kx++) {
                        float wv = w[(t6 - 1) * 5 + kx];
#pragma unroll
                        for (int j = 0; j < 14; j++) acc[1][j] += wv * seg[kx + j];
                    }
                }
            }
        }
        const float bb = c1_b[oc];
        float* ob = out2 + ((size_t)b * 6 + oc) * 196 + py * 14 + h * 7;
#pragma unroll
        for (int px = 0; px < 7; px++) {
            float v = 0.25f * (fast_tanh(acc[0][2 * px] + bb) +
                               fast_tanh(acc[0][2 * px + 1] + bb) +
                               fast_tanh(acc[1][2 * px] + bb) +
                               fast_tanh(acc[1][2 * px + 1] + bb));
            ob[px] = v;
        }
    }
}

// ---------------------------------------------------------------------------
// Kernel B: per image: conv3+bias+tanh+pool -> c5+tanh -> fc1+tanh -> fc2
__global__ __launch_bounds__(128) void lenet_back(
    const float* __restrict__ out2,  // [B,6,14,14]
    const float* __restrict__ c3_w,  // [16,6,5,5]
    const float* __restrict__ c3_b,  // [16]
    const float* __restrict__ c5_w,  // [120,16,5,5]
    const float* __restrict__ c5_b,  // [120]
    const float* __restrict__ l1_w,  // [84,120]
    const float* __restrict__ l1_b,  // [84]
    const float* __restrict__ l2_w,  // [10,84]
    const float* __restrict__ l2_b,  // [10]
    float* __restrict__ out)         // [B,10]
{
    __shared__ float a2[6 * 14 * 18];  // rows padded to 18
    __shared__ float a3[400];          // [16,5,5]
    __shared__ float f5[120];
    __shared__ float f6[84];

    const int b = blockIdx.x;
    const int tid = threadIdx.x;

    for (int i = tid; i < 1176; i += 128) {
        int row = i / 14, c = i % 14;
        a2[row * 18 + c] = out2[(size_t)b * 1176 + i];
    }
    __syncthreads();

    // conv3 + tanh + pool: 400 tasks (oc,py,px pooled)
    for (int t = tid; t < 400; t += 128) {
        const int oc = t / 25;
        const int rr = t % 25;
        const int py = rr / 5, px = rr % 5;
        const int x0 = px * 2, y0 = py * 2;
        float a00 = 0.f, a01 = 0.f, a10 = 0.f, a11 = 0.f;
#pragma unroll 1
        for (int ic = 0; ic < 6; ic++) {
            const float* wr = c3_w + (oc * 6 + ic) * 25;
            float w[25];
#pragma unroll
            for (int q = 0; q < 25; q++) w[q] = wr[q];
#pragma unroll
            for (int t6 = 0; t6 < 6; t6++) {
                float seg[6];
                const float2* sp = (const float2*)&a2[(ic * 14 + y0 + t6) * 18 + x0];
#pragma unroll
                for (int q = 0; q < 3; q++) {
                    float2 v = sp[q];
                    seg[2 * q] = v.x; seg[2 * q + 1] = v.y;
                }
                if (t6 < 5) {
#pragma unroll
                    for (int kx = 0; kx < 5; kx++) {
                        float wv = w[t6 * 5 + kx];
                        a00 += wv * seg[kx]; a01 += wv * seg[kx + 1];
                    }
                }
                if (t6 >= 1) {
#pragma unroll
                    for (int kx = 0; kx < 5; kx++) {
                        float wv = w[(t6 - 1) * 5 + kx];
                        a10 += wv * seg[kx]; a11 += wv * seg[kx + 1];
                    }
                }
            }
        }
        const float bb = c3_b[oc];
        a3[t] = 0.25f * (fast_tanh(a00 + bb) + fast_tanh(a01 + bb) +
                         fast_tanh(a10 + bb) + fast_tanh(a11 + bb));
    }
    __syncthreads();

    // c5: 120 dot products over 400
    if (tid < 120) {
        float acc = c5_b[tid];
        const float4* wp = (const float4*)(c5_w + (size_t)tid * 400);
        const float4* ap = (const float4*)a3;
#pragma unroll 4
        for (int q = 0; q < 100; q++) {
            float4 wv = wp[q], av = ap[q];
            acc += wv.x * av.x + wv.y * av.y + wv.z * av.z + wv.w * av.w;
        }
        f5[tid] = fast_tanh(acc);
    }
    __syncthreads();

    // fc1: 84 dots over 120
    if (tid < 84) {
        float acc = l1_b[tid];
        const float4* wp = (const float4*)(l1_w + tid * 120);
        const float4* fp = (const float4*)f5;
#pragma unroll
        for (int q = 0; q < 30; q++) {
            float4 wv = wp[q], fv = fp[q];
            acc += wv.x * fv.x + wv.y * fv.y + wv.z * fv.z + wv.w * fv.w;
        }
        f6[tid] = fast_tanh(acc);
    }
    __syncthreads();

    // fc2: 10 dots over 84
    if (tid < 10) {
        float acc = l2_b[tid];
        const float* wp = l2_w + tid * 84;
#pragma unroll
        for (int q = 0; q < 84; q++) acc += wp[q] * f6[q];
        out[(size_t)b * 10 + tid] = acc;
    }
}

extern "C" void kernel_launch(void* const* d_in, const int* in_sizes, int n_in,
                              void* d_out, int out_size, void* d_ws, size_t ws_size,
                              hipStream_t stream) {
    const float* x       = (const float*)d_in[0];
    const float* filters = (const float*)d_in[1];
    const float* c1_w    = (const float*)d_in[2];
    const float* c1_b    = (const float*)d_in[3];
    const float* c3_w    = (const float*)d_in[4];
    const float* c3_b    = (const float*)d_in[5];
    const float* c5_w    = (const float*)d_in[6];
    const float* c5_b    = (const float*)d_in[7];
    const float* l1_w    = (const float*)d_in[8];
    const float* l1_b    = (const float*)d_in[9];
    const float* l2_w    = (const float*)d_in[10];
    const float* l2_b    = (const float*)d_in[11];
    float* out = (float*)d_out;

    const int B = in_sizes[0] / 1024;

    // workspace layout: [w1pad: 96*28 f32, pad to 16 KB][out2: B*1176 f32]
    float* w1pad = (float*)d_ws;
    float* out2  = (float*)((char*)d_ws + 16384);

    pad_w1_kernel<<<(96 * 28 + 255) / 256, 256, 0, stream>>>(c1_w, w1pad);
    lenet_front<<<B, 256, 0, stream>>>(x, filters, w1pad, c1_b, out2);
    lenet_back<<<B, 128, 0, stream>>>(out2, c3_w, c3_b, c5_w, c5_b,
                                      l1_w, l1_b, l2_w, l2_b, out);
}

// Round 2
// 435.052 us; speedup vs baseline: 1.1010x; 1.1010x over previous
//
#include <hip/hip_runtime.h>
#include <hip/hip_bf16.h>
#include <cstddef>

// fast tanh: 1 - 2/(exp(2x)+1); saturates correctly for |x| large (exp->inf -> 1)
__device__ __forceinline__ float fast_tanh(float x) {
    float e = __expf(2.0f * x);
    return 1.0f - 2.0f / (e + 1.0f);
}

#define S1STRIDE 34  // s1 row stride in floats: 2*S mod 32 = 4 -> <=2-way bank aliasing in phase B

// ---------------------------------------------------------------------------
// small setup kernel: pad c1_w [6*16][25] -> [6*16][28] (zero tail) so phase B
// can use aligned float4 loads.
__global__ void pad_w1_kernel(const float* __restrict__ src, float* __restrict__ dst) {
    int i = blockIdx.x * blockDim.x + threadIdx.x;
    if (i < 96 * 28) {
        int row = i / 28, t = i % 28;
        dst[i] = (t < 25) ? src[row * 25 + t] : 0.0f;
    }
}

// ---------------------------------------------------------------------------
// Kernel A: per image: conv0(SAME,5x5,1->16)+tanh in LDS, then
// conv1(VALID,5x5,16->6)+bias+tanh+avgpool2 -> out2 [B,6,14,14]
__global__ __launch_bounds__(256, 2) void lenet_front(
    const float* __restrict__ x,        // [B,1,32,32]
    const float* __restrict__ filters,  // [16,1,5,5]
    const float* __restrict__ w1pad,    // [96,28]
    const float* __restrict__ c1_b,     // [6]
    float* __restrict__ out2)           // [B,6,14,14]
{
    __shared__ float xs[36 * 36];                 // zero-padded input
    __shared__ float s1[16 * 32 * S1STRIDE];      // tanh(conv0), 16 ch

    const int b = blockIdx.x;
    const int tid = threadIdx.x;
    const float* xb = x + (size_t)b * 1024;

    for (int i = tid; i < 36 * 36; i += 256) xs[i] = 0.0f;
    __syncthreads();
    for (int i = tid; i < 1024; i += 256) {
        int r = i >> 5, c = i & 31;
        xs[(r + 2) * 36 + (c + 2)] = xb[i];
    }
    __syncthreads();

    // ---- Phase A: conv0 + tanh. 256 tasks: (y, 4-pixel group) ----
    {
        const int y = tid >> 3;
        const int x0 = (tid & 7) * 4;
        float win[40];  // 5 rows x 8 cols
#pragma unroll
        for (int i = 0; i < 5; i++) {
            const float4* p = (const float4*)&xs[(y + i) * 36 + x0];
            float4 a = p[0], q = p[1];
            win[i * 8 + 0] = a.x; win[i * 8 + 1] = a.y;
            win[i * 8 + 2] = a.z; win[i * 8 + 3] = a.w;
            win[i * 8 + 4] = q.x; win[i * 8 + 5] = q.y;
            win[i * 8 + 6] = q.z; win[i * 8 + 7] = q.w;
        }
#pragma unroll
        for (int oc = 0; oc < 16; oc++) {
            float a0 = 0.f, a1 = 0.f, a2 = 0.f, a3 = 0.f;
#pragma unroll
            for (int ky = 0; ky < 5; ky++) {
#pragma unroll
                for (int kx = 0; kx < 5; kx++) {
                    float w = filters[oc * 25 + ky * 5 + kx];  // uniform -> s_load
                    const float* wr = &win[ky * 8 + kx];
                    a0 += w * wr[0]; a1 += w * wr[1];
                    a2 += w * wr[2]; a3 += w * wr[3];
                }
            }
            int base = (oc * 32 + y) * S1STRIDE + x0;  // even -> float2 aligned
            *(float2*)&s1[base]     = make_float2(fast_tanh(a0), fast_tanh(a1));
            *(float2*)&s1[base + 2] = make_float2(fast_tanh(a2), fast_tanh(a3));
        }
    }
    __syncthreads();

    // ---- Phase B: conv1 + bias + tanh + avgpool. 168 tasks: (oc, py, half) ----
    if (tid < 168) {
        const int oc = tid / 28;
        const int r = tid % 28;
        const int py = r >> 1;
        const int h = r & 1;
        const int x0 = h * 14;   // conv col base (14 conv cols -> 7 pooled)
        const int y0 = py * 2;   // conv row base (2 conv rows -> 1 pooled row)

        float acc[2][14];
#pragma unroll
        for (int i = 0; i < 2; i++)
#pragma unroll
            for (int j = 0; j < 14; j++) acc[i][j] = 0.f;

        const float* wbase = w1pad + oc * 16 * 28;
        // weight double-buffer: wreg holds ic's row; next row prefetched during compute
        float4 wreg[7];
#pragma unroll
        for (int q = 0; q < 7; q++) wreg[q] = ((const float4*)wbase)[q];

#pragma unroll 1
        for (int ic = 0; ic < 16; ic++) {
            float w[28];
#pragma unroll
            for (int q = 0; q < 7; q++) {
                float4 v = wreg[q];
                w[4 * q + 0] = v.x; w[4 * q + 1] = v.y;
                w[4 * q + 2] = v.z; w[4 * q + 3] = v.w;
            }
            // prefetch next ic's weights (wraps to row 0 on last iter, harmless)
            const float4* wnext = (const float4*)(wbase + ((ic + 1) & 15) * 28);
#pragma unroll
            for (int q = 0; q < 7; q++) wreg[q] = wnext[q];

#pragma unroll
            for (int t6 = 0; t6 < 6; t6++) {
                const int iy = y0 + t6;
                float seg[18];
                const float2* sp = (const float2*)&s1[(ic * 32 + iy) * S1STRIDE + x0];
#pragma unroll
                for (int q = 0; q < 9; q++) {
                    float2 v = sp[q];
                    seg[2 * q] = v.x; seg[2 * q + 1] = v.y;
                }
                if (t6 < 5) {  // contributes to conv row y0 with ky=t6
#pragma unroll
                    for (int kx = 0; kx < 5; kx++) {
                        float wv = w[t6 * 5 + kx];
#pragma unroll
                        for (int j = 0; j < 14; j++) acc[0][j] += wv * seg[kx + j];
                    }
                }
                if (t6 >= 1) {  // contributes to conv row y0+1 with ky=t6-1
#pragma unroll
                    for (int kx = 0; kx < 5; kx++) {
                        float wv = w[(t6 - 1) * 5 + kx];
#pragma unroll
                        for (int j = 0; j < 14; j++) acc[1][j] += wv * seg[kx + j];
                    }
                }
            }
        }
        const float bb = c1_b[oc];
        float* ob = out2 + ((size_t)b * 6 + oc) * 196 + py * 14 + h * 7;
#pragma unroll
        for (int px = 0; px < 7; px++) {
            float v = 0.25f * (fast_tanh(acc[0][2 * px] + bb) +
                               fast_tanh(acc[0][2 * px + 1] + bb) +
                               fast_tanh(acc[1][2 * px] + bb) +
                               fast_tanh(acc[1][2 * px + 1] + bb));
            ob[px] = v;
        }
    }
}

// ---------------------------------------------------------------------------
// Kernel B: per image: conv3+bias+tanh+pool -> c5+tanh -> fc1+tanh -> fc2
__global__ __launch_bounds__(256) void lenet_back(
    const float* __restrict__ out2,  // [B,6,14,14]
    const float* __restrict__ c3_w,  // [16,6,5,5]
    const float* __restrict__ c3_b,  // [16]
    const float* __restrict__ c5_w,  // [120,16,5,5]
    const float* __restrict__ c5_b,  // [120]
    const float* __restrict__ l1_w,  // [84,120]
    const float* __restrict__ l1_b,  // [84]
    const float* __restrict__ l2_w,  // [10,84]
    const float* __restrict__ l2_b,  // [10]
    float* __restrict__ out)         // [B,10]
{
    __shared__ float a2[6 * 14 * 18];  // rows padded to 18
    __shared__ float a3[400];          // [16,5,5]
    __shared__ float f5[120];
    __shared__ float f6[84];

    const int b = blockIdx.x;
    const int tid = threadIdx.x;

    for (int i = tid; i < 1176; i += 256) {
        int row = i / 14, c = i % 14;
        a2[row * 18 + c] = out2[(size_t)b * 1176 + i];
    }
    __syncthreads();

    // conv3 + tanh + pool: 400 tasks (oc,py,px pooled)
    for (int t = tid; t < 400; t += 256) {
        const int oc = t / 25;
        const int rr = t % 25;
        const int py = rr / 5, px = rr % 5;
        const int x0 = px * 2, y0 = py * 2;
        float a00 = 0.f, a01 = 0.f, a10 = 0.f, a11 = 0.f;
#pragma unroll 1
        for (int ic = 0; ic < 6; ic++) {
            const float* wr = c3_w + (oc * 6 + ic) * 25;
            float w[25];
#pragma unroll
            for (int q = 0; q < 25; q++) w[q] = wr[q];
#pragma unroll
            for (int t6 = 0; t6 < 6; t6++) {
                float seg[6];
                const float2* sp = (const float2*)&a2[(ic * 14 + y0 + t6) * 18 + x0];
#pragma unroll
                for (int q = 0; q < 3; q++) {
                    float2 v = sp[q];
                    seg[2 * q] = v.x; seg[2 * q + 1] = v.y;
                }
                if (t6 < 5) {
#pragma unroll
                    for (int kx = 0; kx < 5; kx++) {
                        float wv = w[t6 * 5 + kx];
                        a00 += wv * seg[kx]; a01 += wv * seg[kx + 1];
                    }
                }
                if (t6 >= 1) {
#pragma unroll
                    for (int kx = 0; kx < 5; kx++) {
                        float wv = w[(t6 - 1) * 5 + kx];
                        a10 += wv * seg[kx]; a11 += wv * seg[kx + 1];
                    }
                }
            }
        }
        const float bb = c3_b[oc];
        a3[t] = 0.25f * (fast_tanh(a00 + bb) + fast_tanh(a01 + bb) +
                         fast_tanh(a10 + bb) + fast_tanh(a11 + bb));
    }
    __syncthreads();

    // c5: 120 dot products over 400; 2 threads per output, shuffle-combine
    if (tid < 240) {
        const int o = tid >> 1;
        const int part = tid & 1;
        float acc = 0.0f;
        const float4* wp = (const float4*)(c5_w + (size_t)o * 400) + part * 50;
        const float4* ap = ((const float4*)a3) + part * 50;
#pragma unroll 5
        for (int q = 0; q < 50; q++) {
            float4 wv = wp[q], av = ap[q];
            acc += wv.x * av.x + wv.y * av.y + wv.z * av.z + wv.w * av.w;
        }
        acc += __shfl_xor(acc, 1);
        if (part == 0) f5[o] = fast_tanh(acc + c5_b[o]);
    }
    __syncthreads();

    // fc1: 84 dots over 120
    if (tid < 84) {
        float acc = l1_b[tid];
        const float4* wp = (const float4*)(l1_w + tid * 120);
        const float4* fp = (const float4*)f5;
#pragma unroll
        for (int q = 0; q < 30; q++) {
            float4 wv = wp[q], fv = fp[q];
            acc += wv.x * fv.x + wv.y * fv.y + wv.z * fv.z + wv.w * fv.w;
        }
        f6[tid] = fast_tanh(acc);
    }
    __syncthreads();

    // fc2: 10 dots over 84
    if (tid < 10) {
        float acc = l2_b[tid];
        const float* wp = l2_w + tid * 84;
#pragma unroll
        for (int q = 0; q < 84; q++) acc += wp[q] * f6[q];
        out[(size_t)b * 10 + tid] = acc;
    }
}

extern "C" void kernel_launch(void* const* d_in, const int* in_sizes, int n_in,
                              void* d_out, int out_size, void* d_ws, size_t ws_size,
                              hipStream_t stream) {
    const float* x       = (const float*)d_in[0];
    const float* filters = (const float*)d_in[1];
    const float* c1_w    = (const float*)d_in[2];
    const float* c1_b    = (const float*)d_in[3];
    const float* c3_w    = (const float*)d_in[4];
    const float* c3_b    = (const float*)d_in[5];
    const float* c5_w    = (const float*)d_in[6];
    const float* c5_b    = (const float*)d_in[7];
    const float* l1_w    = (const float*)d_in[8];
    const float* l1_b    = (const float*)d_in[9];
    const float* l2_w    = (const float*)d_in[10];
    const float* l2_b    = (const float*)d_in[11];
    float* out = (float*)d_out;

    const int B = in_sizes[0] / 1024;

    // workspace layout: [w1pad: 96*28 f32, pad to 16 KB][out2: B*1176 f32]
    float* w1pad = (float*)d_ws;
    float* out2  = (float*)((char*)d_ws + 16384);

    pad_w1_kernel<<<(96 * 28 + 255) / 256, 256, 0, stream>>>(c1_w, w1pad);
    lenet_front<<<B, 256, 0, stream>>>(x, filters, w1pad, c1_b, out2);
    lenet_back<<<B, 256, 0, stream>>>(out2, c3_w, c3_b, c5_w, c5_b,
                                      l1_w, l1_b, l2_w, l2_b, out);
}

// Round 3
// 394.995 us; speedup vs baseline: 1.2126x; 1.1014x over previous
//
#include <hip/hip_runtime.h>
#include <hip/hip_bf16.h>
#include <cstddef>

// fast tanh: 1 - 2/(exp(2x)+1); saturates correctly for |x| large (exp->inf -> 1)
__device__ __forceinline__ float fast_tanh(float x) {
    float e = __expf(2.0f * x);
    return 1.0f - 2.0f / (e + 1.0f);
}

__device__ __forceinline__ float bf2f_lo(unsigned int u) {
    return __uint_as_float(u << 16);
}
__device__ __forceinline__ float bf2f_hi(unsigned int u) {
    return __uint_as_float(u & 0xffff0000u);
}

#define S1S 34  // s1 row stride (bf16 elems); phase-B bank = (2*py+5*seg) mod 32 -> <=2-way

// ---------------------------------------------------------------------------
// pad c1_w [6*16][25] -> [6*16][28] (zero tail) for aligned float4 loads.
__global__ void pad_w1_kernel(const float* __restrict__ src, float* __restrict__ dst) {
    int i = blockIdx.x * blockDim.x + threadIdx.x;
    if (i < 96 * 28) {
        int row = i / 28, t = i % 28;
        dst[i] = (t < 25) ? src[row * 25 + t] : 0.0f;
    }
}

// ---------------------------------------------------------------------------
// Kernel A: per image: conv0(SAME,5x5,1->16)+tanh -> bf16 LDS, then
// conv1(VALID,5x5,16->6)+bias+tanh+avgpool2 -> out2 [B,6,14,14]
// LDS: s1 16*32*34*2 = 34816 B + xs 5184 B = 40000 B -> 4 blocks/CU.
__global__ __launch_bounds__(256, 4) void lenet_front(
    const float* __restrict__ x,        // [B,1,32,32]
    const float* __restrict__ filters,  // [16,1,5,5]
    const float* __restrict__ w1pad,    // [96,28]
    const float* __restrict__ c1_b,     // [6]
    float* __restrict__ out2)           // [B,6,14,14]
{
    __shared__ float xs[36 * 36];                  // zero-padded input
    __shared__ unsigned short s1[16 * 32 * S1S];   // tanh(conv0) as bf16

    const int b = blockIdx.x;
    const int tid = threadIdx.x;
    const float* xb = x + (size_t)b * 1024;

    for (int i = tid; i < 36 * 36; i += 256) xs[i] = 0.0f;
    __syncthreads();
    for (int i = tid; i < 1024; i += 256) {
        int r = i >> 5, c = i & 31;
        xs[(r + 2) * 36 + (c + 2)] = xb[i];
    }
    __syncthreads();

    // ---- Phase A: conv0 + tanh. 256 tasks: (y, 4-pixel group) ----
    {
        const int y = tid >> 3;
        const int x0 = (tid & 7) * 4;
        float win[40];  // 5 rows x 8 cols
#pragma unroll
        for (int i = 0; i < 5; i++) {
            const float4* p = (const float4*)&xs[(y + i) * 36 + x0];
            float4 a = p[0], q = p[1];
            win[i * 8 + 0] = a.x; win[i * 8 + 1] = a.y;
            win[i * 8 + 2] = a.z; win[i * 8 + 3] = a.w;
            win[i * 8 + 4] = q.x; win[i * 8 + 5] = q.y;
            win[i * 8 + 6] = q.z; win[i * 8 + 7] = q.w;
        }
#pragma unroll
        for (int oc = 0; oc < 16; oc++) {
            float a0 = 0.f, a1 = 0.f, a2 = 0.f, a3 = 0.f;
#pragma unroll
            for (int ky = 0; ky < 5; ky++) {
#pragma unroll
                for (int kx = 0; kx < 5; kx++) {
                    float w = filters[oc * 25 + ky * 5 + kx];  // uniform -> s_load
                    const float* wr = &win[ky * 8 + kx];
                    a0 += w * wr[0]; a1 += w * wr[1];
                    a2 += w * wr[2]; a3 += w * wr[3];
                }
            }
            int base = (oc * 32 + y) * S1S + x0;  // even -> 4B aligned
            __hip_bfloat162 p0 = __float22bfloat162_rn(make_float2(fast_tanh(a0), fast_tanh(a1)));
            __hip_bfloat162 p1 = __float22bfloat162_rn(make_float2(fast_tanh(a2), fast_tanh(a3)));
            *reinterpret_cast<__hip_bfloat162*>(&s1[base])     = p0;
            *reinterpret_cast<__hip_bfloat162*>(&s1[base + 2]) = p1;
        }
    }
    __syncthreads();

    // ---- Phase B: conv1 + bias + tanh + avgpool.
    // 252 tasks: (oc in 6) x (pooled row py in 14) x (col segment seg in 3).
    // seg 0,1: 5 pooled cols; seg 2: 4 pooled cols. Each thread: 10 conv cols
    // (seg2 computes 2 garbage cols from valid in-range data, discarded).
    if (tid < 252) {
        const int oc = tid / 42;
        const int r = tid % 42;
        const int py = r / 3;
        const int seg = r % 3;
        const int e0 = 10 * seg;  // input elem base (even)
        const int y0 = 2 * py;    // conv row base

        float acc0[10], acc1[10];
#pragma unroll
        for (int j = 0; j < 10; j++) { acc0[j] = 0.f; acc1[j] = 0.f; }

        const float* wbase = w1pad + oc * 16 * 28;
#pragma unroll 1
        for (int ic = 0; ic < 16; ic++) {
            float w[28];
            const float4* wp = (const float4*)(wbase + ic * 28);
#pragma unroll
            for (int q = 0; q < 7; q++) {
                float4 v = wp[q];
                w[4 * q + 0] = v.x; w[4 * q + 1] = v.y;
                w[4 * q + 2] = v.z; w[4 * q + 3] = v.w;
            }
#pragma unroll
            for (int t6 = 0; t6 < 6; t6++) {
                float segv[14];
                const unsigned int* sp =
                    (const unsigned int*)&s1[(ic * 32 + y0 + t6) * S1S + e0];
#pragma unroll
                for (int q = 0; q < 7; q++) {
                    unsigned int u = sp[q];
                    segv[2 * q] = bf2f_lo(u);
                    segv[2 * q + 1] = bf2f_hi(u);
                }
                if (t6 < 5) {  // conv row y0, ky = t6
#pragma unroll
                    for (int kx = 0; kx < 5; kx++) {
                        float wv = w[t6 * 5 + kx];
#pragma unroll
                        for (int j = 0; j < 10; j++) acc0[j] += wv * segv[kx + j];
                    }
                }
                if (t6 >= 1) {  // conv row y0+1, ky = t6-1
#pragma unroll
                    for (int kx = 0; kx < 5; kx++) {
                        float wv = w[(t6 - 1) * 5 + kx];
#pragma unroll
                        for (int j = 0; j < 10; j++) acc1[j] += wv * segv[kx + j];
                    }
                }
            }
        }
        const float bb = c1_b[oc];
        float* ob = out2 + ((size_t)b * 6 + oc) * 196 + py * 14 + 5 * seg;
#pragma unroll
        for (int p = 0; p < 5; p++) {
            if (5 * seg + p < 14) {
                float v = 0.25f * (fast_tanh(acc0[2 * p] + bb) +
                                   fast_tanh(acc0[2 * p + 1] + bb) +
                                   fast_tanh(acc1[2 * p] + bb) +
                                   fast_tanh(acc1[2 * p + 1] + bb));
                ob[p] = v;
            }
        }
    }
}

// ---------------------------------------------------------------------------
// Kernel B: per image: conv3+bias+tanh+pool -> c5+tanh -> fc1+tanh -> fc2
__global__ __launch_bounds__(256) void lenet_back(
    const float* __restrict__ out2,  // [B,6,14,14]
    const float* __restrict__ c3_w,  // [16,6,5,5]
    const float* __restrict__ c3_b,  // [16]
    const float* __restrict__ c5_w,  // [120,16,5,5]
    const float* __restrict__ c5_b,  // [120]
    const float* __restrict__ l1_w,  // [84,120]
    const float* __restrict__ l1_b,  // [84]
    const float* __restrict__ l2_w,  // [10,84]
    const float* __restrict__ l2_b,  // [10]
    float* __restrict__ out)         // [B,10]
{
    __shared__ float a2[6 * 14 * 18];  // rows padded to 18
    __shared__ float a3[400];          // [16,5,5]
    __shared__ float f5[120];
    __shared__ float f6[84];

    const int b = blockIdx.x;
    const int tid = threadIdx.x;

    for (int i = tid; i < 1176; i += 256) {
        int row = i / 14, c = i % 14;
        a2[row * 18 + c] = out2[(size_t)b * 1176 + i];
    }
    __syncthreads();

    // conv3 + tanh + pool: 400 tasks (oc,py,px pooled)
    for (int t = tid; t < 400; t += 256) {
        const int oc = t / 25;
        const int rr = t % 25;
        const int py = rr / 5, px = rr % 5;
        const int x0 = px * 2, y0 = py * 2;
        float a00 = 0.f, a01 = 0.f, a10 = 0.f, a11 = 0.f;
#pragma unroll 1
        for (int ic = 0; ic < 6; ic++) {
            const float* wr = c3_w + (oc * 6 + ic) * 25;
            float w[25];
#pragma unroll
            for (int q = 0; q < 25; q++) w[q] = wr[q];
#pragma unroll
            for (int t6 = 0; t6 < 6; t6++) {
                float seg[6];
                const float2* sp = (const float2*)&a2[(ic * 14 + y0 + t6) * 18 + x0];
#pragma unroll
                for (int q = 0; q < 3; q++) {
                    float2 v = sp[q];
                    seg[2 * q] = v.x; seg[2 * q + 1] = v.y;
                }
                if (t6 < 5) {
#pragma unroll
                    for (int kx = 0; kx < 5; kx++) {
                        float wv = w[t6 * 5 + kx];
                        a00 += wv * seg[kx]; a01 += wv * seg[kx + 1];
                    }
                }
                if (t6 >= 1) {
#pragma unroll
                    for (int kx = 0; kx < 5; kx++) {
                        float wv = w[(t6 - 1) * 5 + kx];
                        a10 += wv * seg[kx]; a11 += wv * seg[kx + 1];
                    }
                }
            }
        }
        const float bb = c3_b[oc];
        a3[t] = 0.25f * (fast_tanh(a00 + bb) + fast_tanh(a01 + bb) +
                         fast_tanh(a10 + bb) + fast_tanh(a11 + bb));
    }
    __syncthreads();

    // c5: 120 dot products over 400; 2 threads per output, shuffle-combine
    if (tid < 240) {
        const int o = tid >> 1;
        const int part = tid & 1;
        float acc = 0.0f;
        const float4* wp = (const float4*)(c5_w + (size_t)o * 400) + part * 50;
        const float4* ap = ((const float4*)a3) + part * 50;
#pragma unroll 5
        for (int q = 0; q < 50; q++) {
            float4 wv = wp[q], av = ap[q];
            acc += wv.x * av.x + wv.y * av.y + wv.z * av.z + wv.w * av.w;
        }
        acc += __shfl_xor(acc, 1);
        if (part == 0) f5[o] = fast_tanh(acc + c5_b[o]);
    }
    __syncthreads();

    // fc1: 84 dots over 120
    if (tid < 84) {
        float acc = l1_b[tid];
        const float4* wp = (const float4*)(l1_w + tid * 120);
        const float4* fp = (const float4*)f5;
#pragma unroll
        for (int q = 0; q < 30; q++) {
            float4 wv = wp[q], fv = fp[q];
            acc += wv.x * fv.x + wv.y * fv.y + wv.z * fv.z + wv.w * fv.w;
        }
        f6[tid] = fast_tanh(acc);
    }
    __syncthreads();

    // fc2: 10 dots over 84
    if (tid < 10) {
        float acc = l2_b[tid];
        const float* wp = l2_w + tid * 84;
#pragma unroll
        for (int q = 0; q < 84; q++) acc += wp[q] * f6[q];
        out[(size_t)b * 10 + tid] = acc;
    }
}

extern "C" void kernel_launch(void* const* d_in, const int* in_sizes, int n_in,
                              void* d_out, int out_size, void* d_ws, size_t ws_size,
                              hipStream_t stream) {
    const float* x       = (const float*)d_in[0];
    const float* filters = (const float*)d_in[1];
    const float* c1_w    = (const float*)d_in[2];
    const float* c1_b    = (const float*)d_in[3];
    const float* c3_w    = (const float*)d_in[4];
    const float* c3_b    = (const float*)d_in[5];
    const float* c5_w    = (const float*)d_in[6];
    const float* c5_b    = (const float*)d_in[7];
    const float* l1_w    = (const float*)d_in[8];
    const float* l1_b    = (const float*)d_in[9];
    const float* l2_w    = (const float*)d_in[10];
    const float* l2_b    = (const float*)d_in[11];
    float* out = (float*)d_out;

    const int B = in_sizes[0] / 1024;

    // workspace layout: [w1pad: 96*28 f32, pad to 16 KB][out2: B*1176 f32]
    float* w1pad = (float*)d_ws;
    float* out2  = (float*)((char*)d_ws + 16384);

    pad_w1_kernel<<<(96 * 28 + 255) / 256, 256, 0, stream>>>(c1_w, w1pad);
    lenet_front<<<B, 256, 0, stream>>>(x, filters, w1pad, c1_b, out2);
    lenet_back<<<B, 256, 0, stream>>>(out2, c3_w, c3_b, c5_w, c5_b,
                                      l1_w, l1_b, l2_w, l2_b, out);
}

// Round 4
// 339.534 us; speedup vs baseline: 1.4107x; 1.1633x over previous
//
#include <hip/hip_runtime.h>
#include <hip/hip_bf16.h>
#include <cstddef>

typedef _Float16 h2 __attribute__((ext_vector_type(2)));

// fast tanh: 1 - 2/(exp(2x)+1); saturates correctly for |x| large
__device__ __forceinline__ float fast_tanh(float x) {
    float e = __expf(2.0f * x);
    return 1.0f - 2.0f / (e + 1.0f);
}

// v_dot2_f32_f16: a.x*b.x + a.y*b.y + c, f32 accumulate
__device__ __forceinline__ float fdot2u(unsigned int a, unsigned int b, float c) {
    union U { unsigned int u; h2 h; };
    U ua; ua.u = a;
    U ub; ub.u = b;
    return __builtin_amdgcn_fdot2(ua.h, ub.h, c, false);
}

__device__ __forceinline__ unsigned int pkh(float a, float b) {
    union { _Float16 h; unsigned short u; } x, y;
    x.h = (_Float16)a; y.h = (_Float16)b;
    return ((unsigned int)y.u << 16) | (unsigned int)x.u;
}

// ---------------------------------------------------------------------------
// setup: pack conv weights into f16-pair lookup tables.
// per (row of 5 taps): t0=(w0,w1) t1=(w2,w3) t2=(w4,0) | t3=(0,w0) t4=(w1,w2) t5=(w3,w4)
// w1pk: [6][16][32] u32 (ky*6+t, pad 30..31)   f0pk: [16][5][6] u32
__global__ void pack_weights(const float* __restrict__ c1_w,
                             const float* __restrict__ filters,
                             unsigned int* __restrict__ w1pk,
                             unsigned int* __restrict__ f0pk) {
    int t = blockIdx.x * blockDim.x + threadIdx.x;
    if (t < 480) {
        int oc = t / 80, rem = t % 80, ic = rem / 5, ky = rem % 5;
        const float* w = c1_w + (oc * 16 + ic) * 25 + ky * 5;
        unsigned int* d = w1pk + (oc * 16 + ic) * 32 + ky * 6;
        d[0] = pkh(w[0], w[1]); d[1] = pkh(w[2], w[3]); d[2] = pkh(w[4], 0.f);
        d[3] = pkh(0.f, w[0]); d[4] = pkh(w[1], w[2]); d[5] = pkh(w[3], w[4]);
        if (ky == 0) {
            unsigned int* p = w1pk + (oc * 16 + ic) * 32;
            p[30] = 0u; p[31] = 0u;
        }
    } else if (t < 560) {
        int i = t - 480; int oc = i / 5, ky = i % 5;
        const float* w = filters + oc * 25 + ky * 5;
        unsigned int* d = f0pk + oc * 30 + ky * 6;
        d[0] = pkh(w[0], w[1]); d[1] = pkh(w[2], w[3]); d[2] = pkh(w[4], 0.f);
        d[3] = pkh(0.f, w[0]); d[4] = pkh(w[1], w[2]); d[5] = pkh(w[3], w[4]);
    }
}

// ---------------------------------------------------------------------------
// Kernel A: conv0(SAME,5x5,1->16)+tanh -> f16 LDS, then
// conv1(VALID,5x5,16->6)+bias+tanh+avgpool2 -> out2 [B,6,14,14]
// LDS: s1u 16*32*17*4 = 34816 B + xs2 36*18*4 = 2592 B -> 4 blocks/CU
__global__ __launch_bounds__(256, 4) void lenet_front(
    const float* __restrict__ x,          // [B,1,32,32]
    const unsigned int* __restrict__ f0pk,
    const unsigned int* __restrict__ w1pk,
    const float* __restrict__ c1_b,       // [6]
    float* __restrict__ out2)             // [B,6,14,14]
{
    __shared__ unsigned int xs2[36 * 18];     // padded input, f16 pairs
    __shared__ unsigned int s1u[16 * 32 * 17];// tanh(conv0), f16 pairs, 34-col rows

    const int b = blockIdx.x;
    const int tid = threadIdx.x;
    const float* xb = x + (size_t)b * 1024;

    for (int i = tid; i < 36 * 18; i += 256) xs2[i] = 0u;
    __syncthreads();
    for (int i = tid; i < 512; i += 256) {
        int r = i >> 4, c2 = i & 15;
        const float2 v = *(const float2*)(xb + r * 32 + c2 * 2);
        xs2[(r + 2) * 18 + c2 + 1] = pkh(v.x, v.y);
    }
    __syncthreads();

    // ---- Phase A: conv0 + tanh. 256 tasks: (y, 4-col group) ----
    {
        const int y = tid >> 3;
        const int x0h = (tid & 7) * 2;  // u32 col base
        unsigned int win2[5][4];
#pragma unroll
        for (int i = 0; i < 5; i++) {
            const uint2* p = (const uint2*)&xs2[(y + i) * 18 + x0h];
            uint2 a = p[0], bqq = p[1];
            win2[i][0] = a.x; win2[i][1] = a.y; win2[i][2] = bqq.x; win2[i][3] = bqq.y;
        }
#pragma unroll 1
        for (int oc = 0; oc < 16; oc++) {
            const unsigned int* fw = f0pk + oc * 30;  // uniform -> s_load
            float a0 = 0.f, a1 = 0.f, a2 = 0.f, a3 = 0.f;
#pragma unroll
            for (int ky = 0; ky < 5; ky++) {
                unsigned int w01 = fw[ky * 6 + 0], w23 = fw[ky * 6 + 1], w4z = fw[ky * 6 + 2];
                unsigned int zw0 = fw[ky * 6 + 3], w12 = fw[ky * 6 + 4], w34 = fw[ky * 6 + 5];
                a0 = fdot2u(w01, win2[ky][0], a0);
                a0 = fdot2u(w23, win2[ky][1], a0);
                a0 = fdot2u(w4z, win2[ky][2], a0);
                a1 = fdot2u(zw0, win2[ky][0], a1);
                a1 = fdot2u(w12, win2[ky][1], a1);
                a1 = fdot2u(w34, win2[ky][2], a1);
                a2 = fdot2u(w01, win2[ky][1], a2);
                a2 = fdot2u(w23, win2[ky][2], a2);
                a2 = fdot2u(w4z, win2[ky][3], a2);
                a3 = fdot2u(zw0, win2[ky][1], a3);
                a3 = fdot2u(w12, win2[ky][2], a3);
                a3 = fdot2u(w34, win2[ky][3], a3);
            }
            int base = (oc * 32 + y) * 17 + x0h;
            s1u[base]     = pkh(fast_tanh(a0), fast_tanh(a1));
            s1u[base + 1] = pkh(fast_tanh(a2), fast_tanh(a3));
        }
    }
    __syncthreads();

    // ---- Phase B: conv1 + bias + tanh + avgpool.
    // 252 tasks: (oc in 6) x (pooled row py in 14) x (col segment seg in 3).
    if (tid < 252) {
        const int oc = tid / 42;
        const int r = tid % 42;
        const int py = r / 3;
        const int seg = r % 3;
        const int q0 = 5 * seg;  // u32 col base (10 f16 cols)
        const int y0 = 2 * py;

        float acc0[10], acc1[10];
#pragma unroll
        for (int j = 0; j < 10; j++) { acc0[j] = 0.f; acc1[j] = 0.f; }

        const uint4* wb = (const uint4*)(w1pk + oc * 16 * 32);
#pragma unroll 1
        for (int ic = 0; ic < 16; ic++) {
            unsigned int wu[32];
#pragma unroll
            for (int q = 0; q < 8; q++) {
                uint4 v = wb[ic * 8 + q];
                wu[4 * q + 0] = v.x; wu[4 * q + 1] = v.y;
                wu[4 * q + 2] = v.z; wu[4 * q + 3] = v.w;
            }
#pragma unroll
            for (int t6 = 0; t6 < 6; t6++) {
                unsigned int sp[7];
                const unsigned int* srow = &s1u[(ic * 32 + y0 + t6) * 17 + q0];
#pragma unroll
                for (int q = 0; q < 7; q++) sp[q] = srow[q];
                if (t6 < 5) {
                    const int kb = t6 * 6;
#pragma unroll
                    for (int p = 0; p < 5; p++) {
                        acc0[2 * p]     = fdot2u(wu[kb + 0], sp[p],     acc0[2 * p]);
                        acc0[2 * p]     = fdot2u(wu[kb + 1], sp[p + 1], acc0[2 * p]);
                        acc0[2 * p]     = fdot2u(wu[kb + 2], sp[p + 2], acc0[2 * p]);
                        acc0[2 * p + 1] = fdot2u(wu[kb + 3], sp[p],     acc0[2 * p + 1]);
                        acc0[2 * p + 1] = fdot2u(wu[kb + 4], sp[p + 1], acc0[2 * p + 1]);
                        acc0[2 * p + 1] = fdot2u(wu[kb + 5], sp[p + 2], acc0[2 * p + 1]);
                    }
                }
                if (t6 >= 1) {
                    const int kb = (t6 - 1) * 6;
#pragma unroll
                    for (int p = 0; p < 5; p++) {
                        acc1[2 * p]     = fdot2u(wu[kb + 0], sp[p],     acc1[2 * p]);
                        acc1[2 * p]     = fdot2u(wu[kb + 1], sp[p + 1], acc1[2 * p]);
                        acc1[2 * p]     = fdot2u(wu[kb + 2], sp[p + 2], acc1[2 * p]);
                        acc1[2 * p + 1] = fdot2u(wu[kb + 3], sp[p],     acc1[2 * p + 1]);
                        acc1[2 * p + 1] = fdot2u(wu[kb + 4], sp[p + 1], acc1[2 * p + 1]);
                        acc1[2 * p + 1] = fdot2u(wu[kb + 5], sp[p + 2], acc1[2 * p + 1]);
                    }
                }
            }
        }
        const float bb = c1_b[oc];
        float* ob = out2 + ((size_t)b * 6 + oc) * 196 + py * 14 + 5 * seg;
#pragma unroll
        for (int p = 0; p < 5; p++) {
            if (5 * seg + p < 14) {
                float v = 0.25f * (fast_tanh(acc0[2 * p] + bb) +
                                   fast_tanh(acc0[2 * p + 1] + bb) +
                                   fast_tanh(acc1[2 * p] + bb) +
                                   fast_tanh(acc1[2 * p + 1] + bb));
                ob[p] = v;
            }
        }
    }
}

// ---------------------------------------------------------------------------
// Kernel B: per image: conv3+bias+tanh+pool -> c5+tanh -> fc1+tanh -> fc2
__global__ __launch_bounds__(256) void lenet_back(
    const float* __restrict__ out2,  // [B,6,14,14]
    const float* __restrict__ c3_w,  // [16,6,5,5]
    const float* __restrict__ c3_b,  // [16]
    const float* __restrict__ c5_w,  // [120,16,5,5]
    const float* __restrict__ c5_b,  // [120]
    const float* __restrict__ l1_w,  // [84,120]
    const float* __restrict__ l1_b,  // [84]
    const float* __restrict__ l2_w,  // [10,84]
    const float* __restrict__ l2_b,  // [10]
    float* __restrict__ out)         // [B,10]
{
    __shared__ float a2[6 * 14 * 18];  // rows padded to 18
    __shared__ float a3[400];          // [16,5,5]
    __shared__ float f5[120];
    __shared__ float f6[84];

    const int b = blockIdx.x;
    const int tid = threadIdx.x;

    for (int i = tid; i < 1176; i += 256) {
        int row = i / 14, c = i % 14;
        a2[row * 18 + c] = out2[(size_t)b * 1176 + i];
    }
    __syncthreads();

    // conv3 + tanh + pool: 400 tasks (oc,py,px pooled)
    for (int t = tid; t < 400; t += 256) {
        const int oc = t / 25;
        const int rr = t % 25;
        const int py = rr / 5, px = rr % 5;
        const int x0 = px * 2, y0 = py * 2;
        float a00 = 0.f, a01 = 0.f, a10 = 0.f, a11 = 0.f;
#pragma unroll 1
        for (int ic = 0; ic < 6; ic++) {
            const float* wr = c3_w + (oc * 6 + ic) * 25;
            float w[25];
#pragma unroll
            for (int q = 0; q < 25; q++) w[q] = wr[q];
#pragma unroll
            for (int t6 = 0; t6 < 6; t6++) {
                float seg[6];
                const float2* sp = (const float2*)&a2[(ic * 14 + y0 + t6) * 18 + x0];
#pragma unroll
                for (int q = 0; q < 3; q++) {
                    float2 v = sp[q];
                    seg[2 * q] = v.x; seg[2 * q + 1] = v.y;
                }
                if (t6 < 5) {
#pragma unroll
                    for (int kx = 0; kx < 5; kx++) {
                        float wv = w[t6 * 5 + kx];
                        a00 += wv * seg[kx]; a01 += wv * seg[kx + 1];
                    }
                }
                if (t6 >= 1) {
#pragma unroll
                    for (int kx = 0; kx < 5; kx++) {
                        float wv = w[(t6 - 1) * 5 + kx];
                        a10 += wv * seg[kx]; a11 += wv * seg[kx + 1];
                    }
                }
            }
        }
        const float bb = c3_b[oc];
        a3[t] = 0.25f * (fast_tanh(a00 + bb) + fast_tanh(a01 + bb) +
                         fast_tanh(a10 + bb) + fast_tanh(a11 + bb));
    }
    __syncthreads();

    // c5: 120 dot products over 400; 2 threads per output, shuffle-combine
    if (tid < 240) {
        const int o = tid >> 1;
        const int part = tid & 1;
        float acc = 0.0f;
        const float4* wp = (const float4*)(c5_w + (size_t)o * 400) + part * 50;
        const float4* ap = ((const float4*)a3) + part * 50;
#pragma unroll 5
        for (int q = 0; q < 50; q++) {
            float4 wv = wp[q], av = ap[q];
            acc += wv.x * av.x + wv.y * av.y + wv.z * av.z + wv.w * av.w;
        }
        acc += __shfl_xor(acc, 1);
        if (part == 0) f5[o] = fast_tanh(acc + c5_b[o]);
    }
    __syncthreads();

    // fc1: 84 dots over 120
    if (tid < 84) {
        float acc = l1_b[tid];
        const float4* wp = (const float4*)(l1_w + tid * 120);
        const float4* fp = (const float4*)f5;
#pragma unroll
        for (int q = 0; q < 30; q++) {
            float4 wv = wp[q], fv = fp[q];
            acc += wv.x * fv.x + wv.y * fv.y + wv.z * fv.z + wv.w * fv.w;
        }
        f6[tid] = fast_tanh(acc);
    }
    __syncthreads();

    // fc2: 10 dots over 84
    if (tid < 10) {
        float acc = l2_b[tid];
        const float* wp = l2_w + tid * 84;
#pragma unroll
        for (int q = 0; q < 84; q++) acc += wp[q] * f6[q];
        out[(size_t)b * 10 + tid] = acc;
    }
}

extern "C" void kernel_launch(void* const* d_in, const int* in_sizes, int n_in,
                              void* d_out, int out_size, void* d_ws, size_t ws_size,
                              hipStream_t stream) {
    const float* x       = (const float*)d_in[0];
    const float* filters = (const float*)d_in[1];
    const float* c1_w    = (const float*)d_in[2];
    const float* c1_b    = (const float*)d_in[3];
    const float* c3_w    = (const float*)d_in[4];
    const float* c3_b    = (const float*)d_in[5];
    const float* c5_w    = (const float*)d_in[6];
    const float* c5_b    = (const float*)d_in[7];
    const float* l1_w    = (const float*)d_in[8];
    const float* l1_b    = (const float*)d_in[9];
    const float* l2_w    = (const float*)d_in[10];
    const float* l2_b    = (const float*)d_in[11];
    float* out = (float*)d_out;

    const int B = in_sizes[0] / 1024;

    // ws layout: [w1pk: 6*16*32 u32 = 12288 B][f0pk: 480 u32 = 1920 B] pad to 16 KB, [out2]
    unsigned int* w1pk = (unsigned int*)d_ws;
    unsigned int* f0pk = (unsigned int*)((char*)d_ws + 12288);
    float* out2 = (float*)((char*)d_ws + 16384);

    pack_weights<<<3, 256, 0, stream>>>(c1_w, filters, w1pk, f0pk);
    lenet_front<<<B, 256, 0, stream>>>(x, f0pk, w1pk, c1_b, out2);
    lenet_back<<<B, 256, 0, stream>>>(out2, c3_w, c3_b, c5_w, c5_b,
                                      l1_w, l1_b, l2_w, l2_b, out);
}

// Round 5
// 318.242 us; speedup vs baseline: 1.5051x; 1.0669x over previous
//
#include <hip/hip_runtime.h>
#include <hip/hip_bf16.h>
#include <cstddef>

typedef _Float16 h2 __attribute__((ext_vector_type(2)));
typedef _Float16 half8 __attribute__((ext_vector_type(8)));
typedef float f32x4 __attribute__((ext_vector_type(4)));

__device__ __forceinline__ float fast_tanh(float x) {
    float e = __expf(2.0f * x);
    return 1.0f - 2.0f / (e + 1.0f);
}

__device__ __forceinline__ float fdot2u(unsigned int a, unsigned int b, float c) {
    union U { unsigned int u; h2 h; };
    U ua; ua.u = a;
    U ub; ub.u = b;
    return __builtin_amdgcn_fdot2(ua.h, ub.h, c, false);
}

__device__ __forceinline__ unsigned int pkh(float a, float b) {
    union { _Float16 h; unsigned short u; } x, y;
    x.h = (_Float16)a; y.h = (_Float16)b;
    return ((unsigned int)y.u << 16) | (unsigned int)x.u;
}

// K-slot permutation for conv1 MFMA (K=32 per ic):
// pair p (slots 2p,2p+1): p<10: taps (row p>>1, cols 2(p&1), 2(p&1)+1)
//                         p=10..14: (row p-10, col 4) + zero ; p=15: zero,zero
#define S1D 33  // s1p row stride in dwords

// ---------------------------------------------------------------------------
// pack: f0pk (conv0 dot2 pairs) + w1mf (conv1 MFMA A-frags, f16, zero-padded)
__global__ void pack_weights(const float* __restrict__ c1_w,
                             const float* __restrict__ filters,
                             unsigned int* __restrict__ f0pk,   // [16][5][6]
                             unsigned int* __restrict__ w1mf) { // [16ic][4h][16oc][4d]
    int t = blockIdx.x * blockDim.x + threadIdx.x;
    if (t < 80) {
        int oc = t / 5, ky = t % 5;
        const float* w = filters + oc * 25 + ky * 5;
        unsigned int* d = f0pk + oc * 30 + ky * 6;
        d[0] = pkh(w[0], w[1]); d[1] = pkh(w[2], w[3]); d[2] = pkh(w[4], 0.f);
        d[3] = pkh(0.f, w[0]); d[4] = pkh(w[1], w[2]); d[5] = pkh(w[3], w[4]);
    } else if (t >= 256 && t < 256 + 4096) {
        int g = t - 256;
        int d = g & 3, oc = (g >> 2) & 15, h = (g >> 6) & 3, ic = g >> 8;
        int p = 4 * h + d;
        float w0 = 0.f, w1 = 0.f;
        if (oc < 6) {
            const float* w = c1_w + (oc * 16 + ic) * 25;
            if (p < 10) {
                int ty = p >> 1, txb = 2 * (p & 1);
                w0 = w[ty * 5 + txb]; w1 = w[ty * 5 + txb + 1];
            } else if (p < 15) {
                w0 = w[(p - 10) * 5 + 4];
            }
        }
        w1mf[g] = pkh(w0, w1);
    }
}

// ---------------------------------------------------------------------------
// Kernel A: conv0(SAME,5x5,1->16)+tanh -> f16 pair-dup LDS, then
// conv1 via MFMA 16x16x32_f16 + bias + tanh + avgpool2 -> out2 [B,6,14,14]
// LDS: s1p 16*32*33*4 = 67584 B + xs2 36*19*4 = 2736 B -> 2 blocks/CU
__global__ __launch_bounds__(256, 2) void lenet_front(
    const float* __restrict__ x,            // [B,1,32,32]
    const unsigned int* __restrict__ f0pk,
    const unsigned int* __restrict__ w1mf,
    const float* __restrict__ c1_b,         // [6]
    float* __restrict__ out2)               // [B,6,14,14]
{
    __shared__ unsigned int xs2[36 * 19];       // padded input, f16 pairs
    __shared__ unsigned int s1p[16 * 32 * S1D]; // tanh(conv0): dword x = (px x, px x+1)

    const int b = blockIdx.x;
    const int tid = threadIdx.x;
    const float* xb = x + (size_t)b * 1024;

    for (int i = tid; i < 36 * 19; i += 256) xs2[i] = 0u;
    __syncthreads();
    for (int i = tid; i < 512; i += 256) {
        int r = i >> 4, c2 = i & 15;
        const float2 v = *(const float2*)(xb + r * 32 + c2 * 2);
        xs2[(r + 2) * 19 + c2 + 1] = pkh(v.x, v.y);
    }
    __syncthreads();

    // ---- Phase A: conv0 + tanh, 5 px/thread, write pair-dup dwords ----
    {
        const int y = tid >> 3;
        const int xg = tid & 7;
        const int x0 = xg * 4;
        const int x0h = xg * 2;
        unsigned int win2[5][5];
#pragma unroll
        for (int i = 0; i < 5; i++) {
            const unsigned int* pr = &xs2[(y + i) * 19 + x0h];
#pragma unroll
            for (int q = 0; q < 5; q++) win2[i][q] = pr[q];
        }
#pragma unroll 1
        for (int oc = 0; oc < 16; oc++) {
            const unsigned int* fw = f0pk + oc * 30;  // uniform -> s_load
            float a0 = 0.f, a1 = 0.f, a2 = 0.f, a3 = 0.f, a4 = 0.f;
#pragma unroll
            for (int ky = 0; ky < 5; ky++) {
                unsigned int w01 = fw[ky * 6 + 0], w23 = fw[ky * 6 + 1], w4z = fw[ky * 6 + 2];
                unsigned int zw0 = fw[ky * 6 + 3], w12 = fw[ky * 6 + 4], w34 = fw[ky * 6 + 5];
                a0 = fdot2u(w01, win2[ky][0], a0);
                a0 = fdot2u(w23, win2[ky][1], a0);
                a0 = fdot2u(w4z, win2[ky][2], a0);
                a1 = fdot2u(zw0, win2[ky][0], a1);
                a1 = fdot2u(w12, win2[ky][1], a1);
                a1 = fdot2u(w34, win2[ky][2], a1);
                a2 = fdot2u(w01, win2[ky][1], a2);
                a2 = fdot2u(w23, win2[ky][2], a2);
                a2 = fdot2u(w4z, win2[ky][3], a2);
                a3 = fdot2u(zw0, win2[ky][1], a3);
                a3 = fdot2u(w12, win2[ky][2], a3);
                a3 = fdot2u(w34, win2[ky][3], a3);
                a4 = fdot2u(w01, win2[ky][2], a4);
                a4 = fdot2u(w23, win2[ky][3], a4);
                a4 = fdot2u(w4z, win2[ky][4], a4);
            }
            float t0 = fast_tanh(a0), t1 = fast_tanh(a1), t2 = fast_tanh(a2);
            float t3 = fast_tanh(a3), t4 = fast_tanh(a4);
            int base = (oc * 32 + y) * S1D + x0;
            s1p[base + 0] = pkh(t0, t1);
            s1p[base + 1] = pkh(t1, t2);
            s1p[base + 2] = pkh(t2, t3);
            s1p[base + 3] = pkh(t3, t4);
        }
    }
    __syncthreads();

    // ---- Phase B: conv1 via MFMA, epilogue bias+tanh+pool via shfl ----
    const int lane = tid & 63;
    const int wid = tid >> 6;
    const int h = lane >> 4;
    const int c = lane & 15;

    // A-fragments: oc = c, k = 8h+j, resident across all tiles
    half8 af[16];
    const half8* w1v = (const half8*)w1mf;
#pragma unroll
    for (int ks = 0; ks < 16; ks++) af[ks] = w1v[(ks * 4 + h) * 16 + c];

    // per-lane B-read dword offsets for my 4 pairs
    int offd[4];
#pragma unroll
    for (int pl = 0; pl < 4; pl++) {
        int p = 4 * h + pl;
        int pp = (p < 15) ? p : 14;
        int ty = (pp < 10) ? (pp >> 1) : (pp - 10);
        int tx = (pp < 10) ? ((pp & 1) * 2) : 4;
        offd[pl] = ty * S1D + tx + c;
    }

    float bias_l[4];
#pragma unroll
    for (int r = 0; r < 4; r++) {
        int rr = 4 * h + r;
        bias_l[r] = c1_b[rr < 6 ? rr : 5];
    }

#pragma unroll 1
    for (int q = wid; q < 28; q += 4) {
        const int py = q >> 1;
        const int xh = q & 1;
        const int x0 = 12 * xh;
        const int yy = 2 * py;

        f32x4 acc0 = {0.f, 0.f, 0.f, 0.f};
        f32x4 acc1 = {0.f, 0.f, 0.f, 0.f};
#pragma unroll
        for (int ks = 0; ks < 16; ks++) {
            const int bb0 = (ks * 32 + yy) * S1D + x0;
            union H8 { unsigned int u[4]; half8 hv; };
            H8 B0, B1;
#pragma unroll
            for (int pl = 0; pl < 4; pl++) {
                B0.u[pl] = s1p[bb0 + offd[pl]];
                B1.u[pl] = s1p[bb0 + S1D + offd[pl]];
            }
            acc0 = __builtin_amdgcn_mfma_f32_16x16x32_f16(af[ks], B0.hv, acc0, 0, 0, 0);
            acc1 = __builtin_amdgcn_mfma_f32_16x16x32_f16(af[ks], B1.hv, acc1, 0, 0, 0);
        }
        // epilogue: C[row=4h+r][col=c]; pool cols (2q,2q+1) via shfl_xor
#pragma unroll
        for (int r = 0; r < 4; r++) {
            int rr = 4 * h + r;
            float t = fast_tanh(acc0[r] + bias_l[r]) + fast_tanh(acc1[r] + bias_l[r]);
            t += __shfl_xor(t, 1);
            int pq = (c >> 1) + 6 * xh;
            bool ok = (rr < 6) && ((c & 1) == 0) && (xh ? (pq >= 7) : (pq <= 6));
            if (ok) out2[((size_t)b * 6 + rr) * 196 + py * 14 + pq] = 0.25f * t;
        }
    }
}

// ---------------------------------------------------------------------------
// Kernel B: per image: conv3+bias+tanh+pool -> c5+tanh -> fc1+tanh -> fc2
__global__ __launch_bounds__(256) void lenet_back(
    const float* __restrict__ out2,  // [B,6,14,14]
    const float* __restrict__ c3_w,  // [16,6,5,5]
    const float* __restrict__ c3_b,  // [16]
    const float* __restrict__ c5_w,  // [120,16,5,5]
    const float* __restrict__ c5_b,  // [120]
    const float* __restrict__ l1_w,  // [84,120]
    const float* __restrict__ l1_b,  // [84]
    const float* __restrict__ l2_w,  // [10,84]
    const float* __restrict__ l2_b,  // [10]
    float* __restrict__ out)         // [B,10]
{
    __shared__ float a2[6 * 14 * 18];
    __shared__ float a3[400];
    __shared__ float f5[120];
    __shared__ float f6[84];

    const int b = blockIdx.x;
    const int tid = threadIdx.x;

    for (int i = tid; i < 1176; i += 256) {
        int row = i / 14, c = i % 14;
        a2[row * 18 + c] = out2[(size_t)b * 1176 + i];
    }
    __syncthreads();

    for (int t = tid; t < 400; t += 256) {
        const int oc = t / 25;
        const int rr = t % 25;
        const int py = rr / 5, px = rr % 5;
        const int x0 = px * 2, y0 = py * 2;
        float a00 = 0.f, a01 = 0.f, a10 = 0.f, a11 = 0.f;
#pragma unroll 1
        for (int ic = 0; ic < 6; ic++) {
            const float* wr = c3_w + (oc * 6 + ic) * 25;
            float w[25];
#pragma unroll
            for (int q = 0; q < 25; q++) w[q] = wr[q];
#pragma unroll
            for (int t6 = 0; t6 < 6; t6++) {
                float seg[6];
                const float2* sp = (const float2*)&a2[(ic * 14 + y0 + t6) * 18 + x0];
#pragma unroll
                for (int q = 0; q < 3; q++) {
                    float2 v = sp[q];
                    seg[2 * q] = v.x; seg[2 * q + 1] = v.y;
                }
                if (t6 < 5) {
#pragma unroll
                    for (int kx = 0; kx < 5; kx++) {
                        float wv = w[t6 * 5 + kx];
                        a00 += wv * seg[kx]; a01 += wv * seg[kx + 1];
                    }
                }
                if (t6 >= 1) {
#pragma unroll
                    for (int kx = 0; kx < 5; kx++) {
                        float wv = w[(t6 - 1) * 5 + kx];
                        a10 += wv * seg[kx]; a11 += wv * seg[kx + 1];
                    }
                }
            }
        }
        const float bb = c3_b[oc];
        a3[t] = 0.25f * (fast_tanh(a00 + bb) + fast_tanh(a01 + bb) +
                         fast_tanh(a10 + bb) + fast_tanh(a11 + bb));
    }
    __syncthreads();

    if (tid < 240) {
        const int o = tid >> 1;
        const int part = tid & 1;
        float acc = 0.0f;
        const float4* wp = (const float4*)(c5_w + (size_t)o * 400) + part * 50;
        const float4* ap = ((const float4*)a3) + part * 50;
#pragma unroll 5
        for (int q = 0; q < 50; q++) {
            float4 wv = wp[q], av = ap[q];
            acc += wv.x * av.x + wv.y * av.y + wv.z * av.z + wv.w * av.w;
        }
        acc += __shfl_xor(acc, 1);
        if (part == 0) f5[o] = fast_tanh(acc + c5_b[o]);
    }
    __syncthreads();

    if (tid < 84) {
        float acc = l1_b[tid];
        const float4* wp = (const float4*)(l1_w + tid * 120);
        const float4* fp = (const float4*)f5;
#pragma unroll
        for (int q = 0; q < 30; q++) {
            float4 wv = wp[q], fv = fp[q];
            acc += wv.x * fv.x + wv.y * fv.y + wv.z * fv.z + wv.w * fv.w;
        }
        f6[tid] = fast_tanh(acc);
    }
    __syncthreads();

    if (tid < 10) {
        float acc = l2_b[tid];
        const float* wp = l2_w + tid * 84;
#pragma unroll
        for (int q = 0; q < 84; q++) acc += wp[q] * f6[q];
        out[(size_t)b * 10 + tid] = acc;
    }
}

extern "C" void kernel_launch(void* const* d_in, const int* in_sizes, int n_in,
                              void* d_out, int out_size, void* d_ws, size_t ws_size,
                              hipStream_t stream) {
    const float* x       = (const float*)d_in[0];
    const float* filters = (const float*)d_in[1];
    const float* c1_w    = (const float*)d_in[2];
    const float* c1_b    = (const float*)d_in[3];
    const float* c3_w    = (const float*)d_in[4];
    const float* c3_b    = (const float*)d_in[5];
    const float* c5_w    = (const float*)d_in[6];
    const float* c5_b    = (const float*)d_in[7];
    const float* l1_w    = (const float*)d_in[8];
    const float* l1_b    = (const float*)d_in[9];
    const float* l2_w    = (const float*)d_in[10];
    const float* l2_b    = (const float*)d_in[11];
    float* out = (float*)d_out;

    const int B = in_sizes[0] / 1024;

    // ws layout: [f0pk: 480 u32 @0, 2048 B][w1mf: 4096 u32 @2048, 16384 B][out2 @18432]
    unsigned int* f0pk = (unsigned int*)d_ws;
    unsigned int* w1mf = (unsigned int*)((char*)d_ws + 2048);
    float* out2 = (float*)((char*)d_ws + 18432);

    pack_weights<<<17, 256, 0, stream>>>(c1_w, filters, f0pk, w1mf);
    lenet_front<<<B, 256, 0, stream>>>(x, f0pk, w1mf, c1_b, out2);
    lenet_back<<<B, 256, 0, stream>>>(out2, c3_w, c3_b, c5_w, c5_b,
                                      l1_w, l1_b, l2_w, l2_b, out);
}